// Round 1
// baseline (626.322 us; speedup 1.0000x reference)
//
#include <hip/hip_runtime.h>
#include <math.h>

// DeepSeek-V3 MoE gate on gfx950.
// Round 1: exact-fp32 split-K GEMM (VALU) + wave-per-token routing kernel.
// fp32 (not bf16 MFMA) because top-k tie gaps (~4e-3 in score space) are
// smaller than bf16 matmul error (~3e-3 logit) -> idx flips would fail absmax.

#define N_EXPERTS 256
#define N_GROUP 8
#define TOPK_GROUP 4
#define TOP_K 8

#define BM 64
#define BN 256
#define BK 16
#define NCHUNK 4

__global__ __launch_bounds__(256, 4)
void gemm_splitk(const float* __restrict__ X, const float* __restrict__ W,
                 float* __restrict__ part, int K, int T) {
    const int m0 = blockIdx.x * BM;
    const int kc = blockIdx.y;
    const int KC = K / NCHUNK;
    const int k0 = kc * KC;

    // LDS tiles stored transposed: [k][m] / [k][n]; +4 pad keeps float4 alignment.
    __shared__ float As[BK][BM + 4];
    __shared__ float Bs[BK][BN + 4];

    const int tid = threadIdx.x;
    const int tm = tid >> 5;   // 0..7  (m-threads)
    const int tn = tid & 31;   // 0..31 (n-threads)
    const int srow = tid >> 2; // 0..63 staging row
    const int skq = tid & 3;   // 0..3  staging k-quad

    float acc[8][8];
#pragma unroll
    for (int i = 0; i < 8; ++i)
#pragma unroll
        for (int j = 0; j < 8; ++j) acc[i][j] = 0.f;

    const float* Xp = X + (long)(m0 + srow) * K + k0 + skq * 4;
    const float* Wp = W + (long)srow * K + k0 + skq * 4;
    const long WRstride = (long)64 * K;

    for (int kt = 0; kt < KC; kt += BK) {
        float4 av = *(const float4*)Xp;
        Xp += BK;
        float4 bv[4];
#pragma unroll
        for (int r = 0; r < 4; ++r)
            bv[r] = *(const float4*)(Wp + r * WRstride);
        Wp += BK;

        __syncthreads();  // previous tile's reads done
#pragma unroll
        for (int j = 0; j < 4; ++j)
            As[skq * 4 + j][srow] = ((const float*)&av)[j];
#pragma unroll
        for (int r = 0; r < 4; ++r)
#pragma unroll
            for (int j = 0; j < 4; ++j)
                Bs[skq * 4 + j][r * 64 + srow] = ((const float*)&bv[r])[j];
        __syncthreads();

#pragma unroll
        for (int kk = 0; kk < BK; ++kk) {
            float4 a0 = *(const float4*)&As[kk][tm * 4];
            float4 a1 = *(const float4*)&As[kk][tm * 4 + 32];
            float4 b0 = *(const float4*)&Bs[kk][tn * 4];
            float4 b1 = *(const float4*)&Bs[kk][tn * 4 + 128];
            float a[8] = {a0.x, a0.y, a0.z, a0.w, a1.x, a1.y, a1.z, a1.w};
            float b[8] = {b0.x, b0.y, b0.z, b0.w, b1.x, b1.y, b1.z, b1.w};
#pragma unroll
            for (int i = 0; i < 8; ++i)
#pragma unroll
                for (int j = 0; j < 8; ++j)
                    acc[i][j] = fmaf(a[i], b[j], acc[i][j]);
        }
    }

    // partial logits -> ws: part[kc][token][expert]
    float* P = part + (long)kc * T * N_EXPERTS;
#pragma unroll
    for (int i = 0; i < 8; ++i) {
        int mi = m0 + tm * 4 + (i & 3) + (i >> 2) * 32;
        float4 lo = make_float4(acc[i][0], acc[i][1], acc[i][2], acc[i][3]);
        float4 hi = make_float4(acc[i][4], acc[i][5], acc[i][6], acc[i][7]);
        *(float4*)(P + (long)mi * N_EXPERTS + tn * 4) = lo;
        *(float4*)(P + (long)mi * N_EXPERTS + tn * 4 + 128) = hi;
    }
}

// One wave (64 lanes) per token; lane l owns experts 4l..4l+3 (group = l>>3).
__global__ __launch_bounds__(256)
void routing_kernel(const float* __restrict__ part, const float* __restrict__ bias,
                    float* __restrict__ out, int T) {
    const int lane = threadIdx.x & 63;
    const int wv = threadIdx.x >> 6;
    const int t = blockIdx.x * 4 + wv;
    if (t >= T) return;
    const long TN = (long)T * N_EXPERTS;

    // sum split-K partials -> logits
    const float* p = part + (long)t * N_EXPERTS + lane * 4;
    float lg[4] = {0.f, 0.f, 0.f, 0.f};
#pragma unroll
    for (int c = 0; c < NCHUNK; ++c) {
        float4 v = *(const float4*)(p + c * TN);
        lg[0] += v.x; lg[1] += v.y; lg[2] += v.z; lg[3] += v.w;
    }
    float4 bv = *(const float4*)(bias + lane * 4);
    const float bb[4] = {bv.x, bv.y, bv.z, bv.w};

    float s[4], sc[4];
#pragma unroll
    for (int j = 0; j < 4; ++j) {
        s[j] = 1.f / (1.f + expf(-lg[j]));  // unbiased score (for weights)
        sc[j] = s[j] + bb[j];               // biased score (for choice)
    }

    // group score = sum of top-2 biased scores within the 32-expert group
    float m1 = fmaxf(sc[0], sc[1]), m2 = fminf(sc[0], sc[1]);
    if (sc[2] > m1) { m2 = m1; m1 = sc[2]; } else m2 = fmaxf(m2, sc[2]);
    if (sc[3] > m1) { m2 = m1; m1 = sc[3]; } else m2 = fmaxf(m2, sc[3]);
#pragma unroll
    for (int o = 1; o <= 4; o <<= 1) {  // butterfly within 8-lane group
        float o1 = __shfl_xor(m1, o);
        float o2 = __shfl_xor(m2, o);
        float n1 = fmaxf(m1, o1);
        float n2 = fmaxf(fminf(m1, o1), fmaxf(m2, o2));
        m1 = n1; m2 = n2;
    }
    float gsum = m1 + m2;

    float gs[8];
#pragma unroll
    for (int g = 0; g < 8; ++g) gs[g] = __shfl(gsum, g * 8);

    // top-4 groups; jax top_k tie-break = lower index first
    int selmask = 0;
#pragma unroll
    for (int g = 0; g < 8; ++g) {
        int rank = 0;
#pragma unroll
        for (int h = 0; h < 8; ++h)
            rank += (gs[h] > gs[g]) || (gs[h] == gs[g] && h < g);
        if (rank < TOPK_GROUP) selmask |= 1 << g;
    }

    const int mygrp = lane >> 3;
    float val[4];
#pragma unroll
    for (int j = 0; j < 4; ++j)
        val[j] = ((selmask >> mygrp) & 1) ? sc[j] : -INFINITY;

    // iterative top-8: wave argmax (value desc, lower expert idx on ties)
    float wsel[TOP_K];
    int isel[TOP_K];
    float denom = 1e-20f;
#pragma unroll
    for (int it = 0; it < TOP_K; ++it) {
        float bvv = val[0];
        int bi = lane * 4;
#pragma unroll
        for (int j = 1; j < 4; ++j)
            if (val[j] > bvv) { bvv = val[j]; bi = lane * 4 + j; }
#pragma unroll
        for (int o = 1; o < 64; o <<= 1) {
            float ov = __shfl_xor(bvv, o);
            int oi = __shfl_xor(bi, o);
            if (ov > bvv || (ov == bvv && oi < bi)) { bvv = ov; bi = oi; }
        }
        isel[it] = bi;  // wave-uniform
        int q = bi & 3, ol = bi >> 2;
        float sv = (q == 0) ? s[0] : (q == 1) ? s[1] : (q == 2) ? s[2] : s[3];
        float w = __shfl(sv, ol);  // unbiased score of the winner
        wsel[it] = w;
        denom += w;
        if (lane == ol) {
            if (q == 0) val[0] = -INFINITY;
            else if (q == 1) val[1] = -INFINITY;
            else if (q == 2) val[2] = -INFINITY;
            else val[3] = -INFINITY;
        }
    }

    if (lane == 0) {
        float scale = 2.5f / denom;
        long base = (long)t * TOP_K;
        long wbase = (long)T * TOP_K + base;
#pragma unroll
        for (int it = 0; it < TOP_K; ++it) {
            out[base + it] = (float)isel[it];
            out[wbase + it] = wsel[it] * scale;
        }
    }
}

extern "C" void kernel_launch(void* const* d_in, const int* in_sizes, int n_in,
                              void* d_out, int out_size, void* d_ws, size_t ws_size,
                              hipStream_t stream) {
    const float* X = (const float*)d_in[0];     // [T, K] fp32
    const float* W = (const float*)d_in[1];     // [256, K] fp32
    const float* bias = (const float*)d_in[2];  // [256] fp32
    float* out = (float*)d_out;                 // [T*8 idx floats][T*8 weights]
    float* part = (float*)d_ws;                 // [NCHUNK][T][256] fp32 = 32 MB

    const int K = in_sizes[1] / N_EXPERTS;  // 7168
    const int T = in_sizes[0] / K;          // 8192

    dim3 g1(T / BM, NCHUNK);
    gemm_splitk<<<g1, 256, 0, stream>>>(X, W, part, K, T);
    routing_kernel<<<T / 4, 256, 0, stream>>>(part, bias, out, T);
}

// Round 3
// 388.383 us; speedup vs baseline: 1.6126x; 1.6126x over previous
//
#include <hip/hip_runtime.h>
#include <math.h>

// DeepSeek-V3 MoE gate on gfx950.
// Round 3: error-compensated FP16 MFMA GEMM (hi + 2^11-scaled lo planes,
// 3 MFMAs, dual accumulator) + routing. Residual ~5e-7 logit (vs 1.1e-5 for
// the round-2 bf16 3-term split, which flipped near-tie rankings).

#define N_EXPERTS 256
#define TOPK_GROUP 4
#define TOP_K 8

#define KDIM 7168
#define BM 64
#define BK 32
#define NCHUNK 4
#define KC (KDIM / NCHUNK)        // 1792
#define KTILES (KC / BK)          // 56 k-tiles per chunk
#define TILE_SHORTS 16384         // per-k-tile Wb blob: [2 planes][4 kq][256 n][8] f16
#define LO_SCALE 2048.0f
#define LO_INV (1.0f / 2048.0f)

typedef _Float16 f16x8 __attribute__((ext_vector_type(8)));  // 8 f16 (4 VGPRs)
typedef float f32x4 __attribute__((ext_vector_type(4)));

// async global->LDS, 16B per lane; dest = wave-uniform base + lane*16
__device__ __forceinline__ void load_lds16(const void* g, void* l) {
    unsigned int loff = __builtin_amdgcn_readfirstlane(
        (unsigned int)(unsigned long long)l);  // low 32b of flat LDS ptr = LDS offset
    __builtin_amdgcn_global_load_lds(
        (const __attribute__((address_space(1))) unsigned int*)g,
        (__attribute__((address_space(3))) unsigned int*)loff,
        16, 0, 0);
}

// W [256][7168] fp32 -> Wb tiles: [tile=k/32][plane hi/lo][kq=(k%32)/8][n][j=k%8] f16
__global__ __launch_bounds__(256)
void convert_w(const float* __restrict__ W, unsigned short* __restrict__ Wb) {
    int g = blockIdx.x * 256 + threadIdx.x;  // 256 n * 896 k8
    int n = g / (KDIM / 8);
    int k8 = g % (KDIM / 8);
    const float* src = W + (long)n * KDIM + k8 * 8;
    float4 v0 = *(const float4*)src;
    float4 v1 = *(const float4*)(src + 4);
    float x[8] = {v0.x, v0.y, v0.z, v0.w, v1.x, v1.y, v1.z, v1.w};
    f16x8 hv, lv;
#pragma unroll
    for (int j = 0; j < 8; ++j) {
        _Float16 h = (_Float16)x[j];
        hv[j] = h;
        lv[j] = (_Float16)((x[j] - (float)h) * LO_SCALE);  // x-h exact (Sterbenz), *2^11 exact
    }
    int tile = k8 >> 2, kq = k8 & 3;
    unsigned short* dh = Wb + (long)tile * TILE_SHORTS + kq * 2048 + n * 8;
    *(f16x8*)dh = hv;
    *(f16x8*)(dh + 8192) = lv;
}

__global__ __launch_bounds__(256, 2)
void gemm_mfma(const float* __restrict__ X, const unsigned short* __restrict__ Wb,
               float* __restrict__ part, int T) {
    // A: [plane][m][40 f16] (pad 32->40 breaks ds_read bank aliasing)
    __shared__ __align__(16) unsigned short As[2][64 * 40];   // 10 KB
    // B: [plane][kq][n][8] — matches k-major frag order, conflict-free, linear staging
    __shared__ __align__(16) unsigned short Bs[2 * 4 * 256 * 8];  // 32 KB

    const int tid = threadIdx.x;
    // XCD swizzle: chunk kc owns XCDs {2kc,2kc+1} so its Wb slice is L2-resident
    const int lin = blockIdx.x;
    const int xcd = lin & 7;
    const int kc = xcd >> 1;
    const int mb = ((lin >> 3) << 1) | (xcd & 1);
    const int m0 = mb * BM;

    const int w = tid >> 6;          // wave 0..3 -> n-range w*64
    const int l = tid & 63;
    const int l16 = l & 15, l4 = l >> 4;

    // A staging: thread handles (m = tid>>2, kq = tid&3), 8 consecutive k
    const int sm = tid >> 2, skq = tid & 3;
    const float* Xp = X + (long)(m0 + sm) * KDIM + kc * KC + skq * 8;

    const unsigned short* WbBase = Wb + (long)(kc * KTILES) * TILE_SHORTS;

    f32x4 acc0[4][4], acc1[4][4];
#pragma unroll
    for (int i = 0; i < 4; ++i)
#pragma unroll
        for (int j = 0; j < 4; ++j) {
            acc0[i][j] = (f32x4){0.f, 0.f, 0.f, 0.f};
            acc1[i][j] = (f32x4){0.f, 0.f, 0.f, 0.f};
        }

    // preload A tile 0
    float4 a0 = *(const float4*)Xp;
    float4 a1 = *(const float4*)(Xp + 4);

    for (int kt = 0; kt < KTILES; ++kt) {
        __syncthreads();  // all waves done reading previous tile

        // B: async 32KB tile; each wave copies a contiguous 8KB
        const unsigned short* bsrc = WbBase + (long)kt * TILE_SHORTS + w * 4096 + l * 8;
        unsigned short* bdst = Bs + w * 4096;
#pragma unroll
        for (int r = 0; r < 8; ++r)
            load_lds16(bsrc + r * 512, bdst + r * 512);

        // A: convert fp32 -> f16 hi + scaled-lo, write to LDS
        {
            float xv[8] = {a0.x, a0.y, a0.z, a0.w, a1.x, a1.y, a1.z, a1.w};
            f16x8 hv, lv;
#pragma unroll
            for (int j = 0; j < 8; ++j) {
                _Float16 h = (_Float16)xv[j];
                hv[j] = h;
                lv[j] = (_Float16)((xv[j] - (float)h) * LO_SCALE);
            }
            *(f16x8*)&As[0][sm * 40 + skq * 8] = hv;
            *(f16x8*)&As[1][sm * 40 + skq * 8] = lv;
        }
        __syncthreads();  // drains vmcnt (global_load_lds) + lgkm (ds_write)

        // prefetch next A tile while MFMAs run
        if (kt + 1 < KTILES) {
            a0 = *(const float4*)(Xp + (kt + 1) * BK);
            a1 = *(const float4*)(Xp + (kt + 1) * BK + 4);
        }

        // fragment loads (all conflict-free b128 reads)
        f16x8 ah[4], al[4], bh[4], bl[4];
#pragma unroll
        for (int i = 0; i < 4; ++i) {
            const char* pa = (const char*)&As[0][0] + (i * 16 + l16) * 80 + l4 * 16;
            ah[i] = *(const f16x8*)pa;
            al[i] = *(const f16x8*)(pa + 5120);
        }
#pragma unroll
        for (int j = 0; j < 4; ++j) {
            const char* pb = (const char*)Bs + l4 * 4096 + (w * 64 + j * 16 + l16) * 16;
            bh[j] = *(const f16x8*)pb;
            bl[j] = *(const f16x8*)(pb + 16384);
        }

#pragma unroll
        for (int i = 0; i < 4; ++i)
#pragma unroll
            for (int j = 0; j < 4; ++j) {
                acc1[i][j] = __builtin_amdgcn_mfma_f32_16x16x32_f16(ah[i], bl[j], acc1[i][j], 0, 0, 0);
                acc1[i][j] = __builtin_amdgcn_mfma_f32_16x16x32_f16(al[i], bh[j], acc1[i][j], 0, 0, 0);
                acc0[i][j] = __builtin_amdgcn_mfma_f32_16x16x32_f16(ah[i], bh[j], acc0[i][j], 0, 0, 0);
            }
    }

    // epilogue: part[kc][m0+m][n]  (C/D layout: col=lane&15, row=(lane>>4)*4+reg)
    float* P = part + ((long)kc * T + m0) * N_EXPERTS;
#pragma unroll
    for (int i = 0; i < 4; ++i) {
        int m = i * 16 + l4 * 4;
        int n = w * 64 + l16;
#pragma unroll
        for (int j = 0; j < 4; ++j)
#pragma unroll
            for (int r = 0; r < 4; ++r)
                P[(long)(m + r) * N_EXPERTS + n + j * 16] =
                    acc0[i][j][r] + acc1[i][j][r] * LO_INV;
    }
}

// One wave (64 lanes) per token; lane l owns experts 4l..4l+3 (group = l>>3).
__global__ __launch_bounds__(256)
void routing_kernel(const float* __restrict__ part, const float* __restrict__ bias,
                    float* __restrict__ out, int T) {
    const int lane = threadIdx.x & 63;
    const int wv = threadIdx.x >> 6;
    const int t = blockIdx.x * 4 + wv;
    if (t >= T) return;
    const long TN = (long)T * N_EXPERTS;

    const float* p = part + (long)t * N_EXPERTS + lane * 4;
    float lg[4] = {0.f, 0.f, 0.f, 0.f};
#pragma unroll
    for (int c = 0; c < NCHUNK; ++c) {
        float4 v = *(const float4*)(p + c * TN);
        lg[0] += v.x; lg[1] += v.y; lg[2] += v.z; lg[3] += v.w;
    }
    float4 bv = *(const float4*)(bias + lane * 4);
    const float bb[4] = {bv.x, bv.y, bv.z, bv.w};

    float s[4], sc[4];
#pragma unroll
    for (int j = 0; j < 4; ++j) {
        s[j] = 1.f / (1.f + expf(-lg[j]));
        sc[j] = s[j] + bb[j];
    }

    // group score = sum of top-2 biased scores within the 32-expert group
    float m1 = fmaxf(sc[0], sc[1]), m2 = fminf(sc[0], sc[1]);
    if (sc[2] > m1) { m2 = m1; m1 = sc[2]; } else m2 = fmaxf(m2, sc[2]);
    if (sc[3] > m1) { m2 = m1; m1 = sc[3]; } else m2 = fmaxf(m2, sc[3]);
#pragma unroll
    for (int o = 1; o <= 4; o <<= 1) {
        float o1 = __shfl_xor(m1, o);
        float o2 = __shfl_xor(m2, o);
        float n1 = fmaxf(m1, o1);
        float n2 = fmaxf(fminf(m1, o1), fmaxf(m2, o2));
        m1 = n1; m2 = n2;
    }
    float gsum = m1 + m2;

    float gs[8];
#pragma unroll
    for (int g = 0; g < 8; ++g) gs[g] = __shfl(gsum, g * 8);

    int selmask = 0;
#pragma unroll
    for (int g = 0; g < 8; ++g) {
        int rank = 0;
#pragma unroll
        for (int h = 0; h < 8; ++h)
            rank += (gs[h] > gs[g]) || (gs[h] == gs[g] && h < g);
        if (rank < TOPK_GROUP) selmask |= 1 << g;
    }

    const int mygrp = lane >> 3;
    float val[4];
#pragma unroll
    for (int j = 0; j < 4; ++j)
        val[j] = ((selmask >> mygrp) & 1) ? sc[j] : -INFINITY;

    float wsel[TOP_K];
    int isel[TOP_K];
    float denom = 1e-20f;
#pragma unroll
    for (int it = 0; it < TOP_K; ++it) {
        float bvv = val[0];
        int bi = lane * 4;
#pragma unroll
        for (int j = 1; j < 4; ++j)
            if (val[j] > bvv) { bvv = val[j]; bi = lane * 4 + j; }
#pragma unroll
        for (int o = 1; o < 64; o <<= 1) {
            float ov = __shfl_xor(bvv, o);
            int oi = __shfl_xor(bi, o);
            if (ov > bvv || (ov == bvv && oi < bi)) { bvv = ov; bi = oi; }
        }
        isel[it] = bi;
        int q = bi & 3, ol = bi >> 2;
        float sv = (q == 0) ? s[0] : (q == 1) ? s[1] : (q == 2) ? s[2] : s[3];
        float w = __shfl(sv, ol);
        wsel[it] = w;
        denom += w;
        if (lane == ol) {
            if (q == 0) val[0] = -INFINITY;
            else if (q == 1) val[1] = -INFINITY;
            else if (q == 2) val[2] = -INFINITY;
            else val[3] = -INFINITY;
        }
    }

    if (lane == 0) {
        float scale = 2.5f / denom;
        long base = (long)t * TOP_K;
        long wbase = (long)T * TOP_K + base;
#pragma unroll
        for (int it = 0; it < TOP_K; ++it) {
            out[base + it] = (float)isel[it];
            out[wbase + it] = wsel[it] * scale;
        }
    }
}

extern "C" void kernel_launch(void* const* d_in, const int* in_sizes, int n_in,
                              void* d_out, int out_size, void* d_ws, size_t ws_size,
                              hipStream_t stream) {
    const float* X = (const float*)d_in[0];     // [T, 7168] fp32
    const float* W = (const float*)d_in[1];     // [256, 7168] fp32
    const float* bias = (const float*)d_in[2];  // [256] fp32
    float* out = (float*)d_out;

    const int K = in_sizes[1] / N_EXPERTS;  // 7168
    const int T = in_sizes[0] / K;          // 8192

    float* part = (float*)d_ws;                                    // 32 MB
    unsigned short* Wb = (unsigned short*)((char*)d_ws + (size_t)NCHUNK * T * N_EXPERTS * 4);  // 7.34 MB

    convert_w<<<(N_EXPERTS * (KDIM / 8)) / 256, 256, 0, stream>>>(W, Wb);
    gemm_mfma<<<(T / BM) * NCHUNK, 256, 0, stream>>>(X, Wb, part, T);
    routing_kernel<<<T / 4, 256, 0, stream>>>(part, bias, out, T);
}

// Round 4
// 375.892 us; speedup vs baseline: 1.6662x; 1.0332x over previous
//
#include <hip/hip_runtime.h>
#include <math.h>

// DeepSeek-V3 MoE gate on gfx950.
// Round 4: B-operand direct global->VGPR (swizzled L2-resident blob, one-tile
// prefetch), A in double-buffered LDS, ONE barrier per K-tile. Kills the
// global_load_lds + vmcnt(0)-drain serialization that capped round 3 at
// MfmaUtil 26%. Numerics unchanged: fp16 hi + 2^11-scaled lo, 3 MFMAs.

#define N_EXPERTS 256
#define TOPK_GROUP 4
#define TOP_K 8

#define KDIM 7168
#define BM 64
#define BK 32
#define NCHUNK 4
#define KC (KDIM / NCHUNK)        // 1792
#define KTILES (KC / BK)          // 56 k-tiles per chunk
// Wb blob: [tile][w 0..3][plane 0..1][j 0..3][l4 0..3][l16 0..15][jj 0..7] f16
// -> per (tile,w,plane,j): 1KB read by 64 lanes as contiguous dwordx4 (l*8 shorts)
#define TILE_SHORTS 16384
#define LO_SCALE 2048.0f
#define LO_INV (1.0f / 2048.0f)

typedef _Float16 f16x8 __attribute__((ext_vector_type(8)));  // 8 f16 (4 VGPRs)
typedef float f32x4 __attribute__((ext_vector_type(4)));

// W [256][7168] fp32 -> swizzled hi/lo f16 blob (see layout above)
__global__ __launch_bounds__(256)
void convert_w(const float* __restrict__ W, unsigned short* __restrict__ Wb) {
    int g = blockIdx.x * 256 + threadIdx.x;  // n * (KDIM/8) + k8
    int n = g / (KDIM / 8);
    int k8 = g % (KDIM / 8);
    const float* src = W + (long)n * KDIM + k8 * 8;
    float4 v0 = *(const float4*)src;
    float4 v1 = *(const float4*)(src + 4);
    float x[8] = {v0.x, v0.y, v0.z, v0.w, v1.x, v1.y, v1.z, v1.w};
    f16x8 hv, lv;
#pragma unroll
    for (int j = 0; j < 8; ++j) {
        _Float16 h = (_Float16)x[j];
        hv[j] = h;
        lv[j] = (_Float16)((x[j] - (float)h) * LO_SCALE);  // exact split, *2^11 exact
    }
    int tk = k8 >> 2, l4 = k8 & 3;
    int w = n >> 6, j = (n >> 4) & 3, l16 = n & 15;
    unsigned short* d = Wb + (long)tk * TILE_SHORTS + w * 4096 + j * 512 + l4 * 128 + l16 * 8;
    *(f16x8*)d = hv;            // plane 0 (hi)
    *(f16x8*)(d + 2048) = lv;   // plane 1 (lo), +pl stride 4*4*128
}

__global__ __launch_bounds__(256, 2)
void gemm_mfma(const float* __restrict__ X, const unsigned short* __restrict__ Wb,
               float* __restrict__ part, int T) {
    // A double-buffered: [buf][plane][m 0..63][40 f16] (pad 32->40), 20 KB total
    __shared__ __align__(16) unsigned short As[2][2][64 * 40];

    const int tid = threadIdx.x;
    // XCD swizzle: chunk kc owns XCDs {2kc,2kc+1} -> its 1.8MB Wb slice L2-resident
    const int lin = blockIdx.x;
    const int xcd = lin & 7;
    const int kc = xcd >> 1;
    const int mb = ((lin >> 3) << 1) | (xcd & 1);
    const int m0 = mb * BM;

    const int w = tid >> 6;          // wave 0..3 -> n-range w*64
    const int l = tid & 63;
    const int l16 = l & 15, l4 = l >> 4;

    // A staging: thread (m = tid>>2, kq = tid&3) loads 8 consecutive k floats
    const int sm = tid >> 2, skq = tid & 3;
    const float* Xp = X + (long)(m0 + sm) * KDIM + kc * KC + skq * 8;

    // B: per-lane base; tile kt frag (pl,j) at +kt*TILE_SHORTS + pl*2048 + j*512
    const unsigned short* Bp = Wb + (long)(kc * KTILES) * TILE_SHORTS + w * 4096 + l * 8;

    f32x4 acc0[4][4], acc1[4][4];
#pragma unroll
    for (int i = 0; i < 4; ++i)
#pragma unroll
        for (int j = 0; j < 4; ++j) {
            acc0[i][j] = (f32x4){0.f, 0.f, 0.f, 0.f};
            acc1[i][j] = (f32x4){0.f, 0.f, 0.f, 0.f};
        }

    f16x8 bcur[8], bnext[8];

    // ---- prologue: tile 0 ----
    {
        float4 xa = *(const float4*)Xp;
        float4 xb = *(const float4*)(Xp + 4);
        float xv[8] = {xa.x, xa.y, xa.z, xa.w, xb.x, xb.y, xb.z, xb.w};
        f16x8 hv, lv;
#pragma unroll
        for (int j = 0; j < 8; ++j) {
            _Float16 h = (_Float16)xv[j];
            hv[j] = h;
            lv[j] = (_Float16)((xv[j] - (float)h) * LO_SCALE);
        }
        *(f16x8*)&As[0][0][sm * 40 + skq * 8] = hv;
        *(f16x8*)&As[0][1][sm * 40 + skq * 8] = lv;
    }
#pragma unroll
    for (int pl = 0; pl < 2; ++pl)
#pragma unroll
        for (int j = 0; j < 4; ++j)
            bcur[pl * 4 + j] = *(const f16x8*)(Bp + pl * 2048 + j * 512);
    float4 xa = *(const float4*)(Xp + BK);       // tile 1
    float4 xb = *(const float4*)(Xp + BK + 4);
    __syncthreads();

    for (int kt = 0; kt < KTILES; ++kt) {
        const int cur = kt & 1, nxt = cur ^ 1;

        if (kt + 1 < KTILES) {
            // stage A(kt+1) into buf[nxt]
            float xv[8] = {xa.x, xa.y, xa.z, xa.w, xb.x, xb.y, xb.z, xb.w};
            f16x8 hv, lv;
#pragma unroll
            for (int j = 0; j < 8; ++j) {
                _Float16 h = (_Float16)xv[j];
                hv[j] = h;
                lv[j] = (_Float16)((xv[j] - (float)h) * LO_SCALE);
            }
            *(f16x8*)&As[nxt][0][sm * 40 + skq * 8] = hv;
            *(f16x8*)&As[nxt][1][sm * 40 + skq * 8] = lv;

            // prefetch B(kt+1) -> regs
            const unsigned short* bp1 = Bp + (long)(kt + 1) * TILE_SHORTS;
#pragma unroll
            for (int pl = 0; pl < 2; ++pl)
#pragma unroll
                for (int j = 0; j < 4; ++j)
                    bnext[pl * 4 + j] = *(const f16x8*)(bp1 + pl * 2048 + j * 512);

            // prefetch X(kt+2) -> regs
            const int kn = (kt + 2 < KTILES) ? kt + 2 : kt + 1;
            xa = *(const float4*)(Xp + kn * BK);
            xb = *(const float4*)(Xp + kn * BK + 4);
        }

        // A fragments from buf[cur] (conflict-light b128 reads)
        f16x8 ah[4], al[4];
#pragma unroll
        for (int i = 0; i < 4; ++i) {
            const char* pa = (const char*)&As[cur][0][0] + (i * 16 + l16) * 80 + l4 * 16;
            ah[i] = *(const f16x8*)pa;
            al[i] = *(const f16x8*)(pa + 5120);
        }

#pragma unroll
        for (int i = 0; i < 4; ++i)
#pragma unroll
            for (int j = 0; j < 4; ++j) {
                acc1[i][j] = __builtin_amdgcn_mfma_f32_16x16x32_f16(ah[i], bcur[4 + j], acc1[i][j], 0, 0, 0);
                acc1[i][j] = __builtin_amdgcn_mfma_f32_16x16x32_f16(al[i], bcur[j], acc1[i][j], 0, 0, 0);
                acc0[i][j] = __builtin_amdgcn_mfma_f32_16x16x32_f16(ah[i], bcur[j], acc0[i][j], 0, 0, 0);
            }

#pragma unroll
        for (int r = 0; r < 8; ++r) bcur[r] = bnext[r];

        __syncthreads();  // buf[nxt] written & buf[cur] consumed; vmcnt drain
                          // only waits on prefetches issued a full tile ago
    }

    // epilogue: part[kc][m0+m][n]  (C/D layout: col=lane&15, row=(lane>>4)*4+reg)
    float* P = part + ((long)kc * T + m0) * N_EXPERTS;
#pragma unroll
    for (int i = 0; i < 4; ++i) {
        int m = i * 16 + l4 * 4;
        int n = w * 64 + l16;
#pragma unroll
        for (int j = 0; j < 4; ++j)
#pragma unroll
            for (int r = 0; r < 4; ++r)
                P[(long)(m + r) * N_EXPERTS + n + j * 16] =
                    acc0[i][j][r] + acc1[i][j][r] * LO_INV;
    }
}

// One wave (64 lanes) per token; lane l owns experts 4l..4l+3 (group = l>>3).
__global__ __launch_bounds__(256)
void routing_kernel(const float* __restrict__ part, const float* __restrict__ bias,
                    float* __restrict__ out, int T) {
    const int lane = threadIdx.x & 63;
    const int wv = threadIdx.x >> 6;
    const int t = blockIdx.x * 4 + wv;
    if (t >= T) return;
    const long TN = (long)T * N_EXPERTS;

    const float* p = part + (long)t * N_EXPERTS + lane * 4;
    float lg[4] = {0.f, 0.f, 0.f, 0.f};
#pragma unroll
    for (int c = 0; c < NCHUNK; ++c) {
        float4 v = *(const float4*)(p + c * TN);
        lg[0] += v.x; lg[1] += v.y; lg[2] += v.z; lg[3] += v.w;
    }
    float4 bv = *(const float4*)(bias + lane * 4);
    const float bb[4] = {bv.x, bv.y, bv.z, bv.w};

    float s[4], sc[4];
#pragma unroll
    for (int j = 0; j < 4; ++j) {
        s[j] = 1.f / (1.f + expf(-lg[j]));
        sc[j] = s[j] + bb[j];
    }

    // group score = sum of top-2 biased scores within the 32-expert group
    float m1 = fmaxf(sc[0], sc[1]), m2 = fminf(sc[0], sc[1]);
    if (sc[2] > m1) { m2 = m1; m1 = sc[2]; } else m2 = fmaxf(m2, sc[2]);
    if (sc[3] > m1) { m2 = m1; m1 = sc[3]; } else m2 = fmaxf(m2, sc[3]);
#pragma unroll
    for (int o = 1; o <= 4; o <<= 1) {
        float o1 = __shfl_xor(m1, o);
        float o2 = __shfl_xor(m2, o);
        float n1 = fmaxf(m1, o1);
        float n2 = fmaxf(fminf(m1, o1), fmaxf(m2, o2));
        m1 = n1; m2 = n2;
    }
    float gsum = m1 + m2;

    float gs[8];
#pragma unroll
    for (int g = 0; g < 8; ++g) gs[g] = __shfl(gsum, g * 8);

    int selmask = 0;
#pragma unroll
    for (int g = 0; g < 8; ++g) {
        int rank = 0;
#pragma unroll
        for (int h = 0; h < 8; ++h)
            rank += (gs[h] > gs[g]) || (gs[h] == gs[g] && h < g);
        if (rank < TOPK_GROUP) selmask |= 1 << g;
    }

    const int mygrp = lane >> 3;
    float val[4];
#pragma unroll
    for (int j = 0; j < 4; ++j)
        val[j] = ((selmask >> mygrp) & 1) ? sc[j] : -INFINITY;

    float wsel[TOP_K];
    int isel[TOP_K];
    float denom = 1e-20f;
#pragma unroll
    for (int it = 0; it < TOP_K; ++it) {
        float bvv = val[0];
        int bi = lane * 4;
#pragma unroll
        for (int j = 1; j < 4; ++j)
            if (val[j] > bvv) { bvv = val[j]; bi = lane * 4 + j; }
#pragma unroll
        for (int o = 1; o < 64; o <<= 1) {
            float ov = __shfl_xor(bvv, o);
            int oi = __shfl_xor(bi, o);
            if (ov > bvv || (ov == bvv && oi < bi)) { bvv = ov; bi = oi; }
        }
        isel[it] = bi;
        int q = bi & 3, ol = bi >> 2;
        float sv = (q == 0) ? s[0] : (q == 1) ? s[1] : (q == 2) ? s[2] : s[3];
        float w = __shfl(sv, ol);
        wsel[it] = w;
        denom += w;
        if (lane == ol) {
            if (q == 0) val[0] = -INFINITY;
            else if (q == 1) val[1] = -INFINITY;
            else if (q == 2) val[2] = -INFINITY;
            else val[3] = -INFINITY;
        }
    }

    if (lane == 0) {
        float scale = 2.5f / denom;
        long base = (long)t * TOP_K;
        long wbase = (long)T * TOP_K + base;
#pragma unroll
        for (int it = 0; it < TOP_K; ++it) {
            out[base + it] = (float)isel[it];
            out[wbase + it] = wsel[it] * scale;
        }
    }
}

extern "C" void kernel_launch(void* const* d_in, const int* in_sizes, int n_in,
                              void* d_out, int out_size, void* d_ws, size_t ws_size,
                              hipStream_t stream) {
    const float* X = (const float*)d_in[0];     // [T, 7168] fp32
    const float* W = (const float*)d_in[1];     // [256, 7168] fp32
    const float* bias = (const float*)d_in[2];  // [256] fp32
    float* out = (float*)d_out;

    const int K = in_sizes[1] / N_EXPERTS;  // 7168
    const int T = in_sizes[0] / K;          // 8192

    float* part = (float*)d_ws;                                    // 32 MB
    unsigned short* Wb = (unsigned short*)((char*)d_ws + (size_t)NCHUNK * T * N_EXPERTS * 4);  // 7.34 MB

    convert_w<<<(N_EXPERTS * (KDIM / 8)) / 256, 256, 0, stream>>>(W, Wb);
    gemm_mfma<<<(T / BM) * NCHUNK, 256, 0, stream>>>(X, Wb, part, T);
    routing_kernel<<<T / 4, 256, 0, stream>>>(part, bias, out, T);
}